// Round 11
// baseline (168.191 us; speedup 1.0000x reference)
//
#include <hip/hip_runtime.h>
#include <hip/hip_bf16.h>

// GRU: B=4096, T=512, I=1, H=32, C=2.
// One 32-lane group per batch element (8 groups / 256-thr block, 2048 waves).
// Lane j owns h[j] and W_hh rows {j,32+j,64+j} as 48 int-packed fp16x2 regs.
// R10 KEY CHANGE vs R9: opaque-def asm pin of all 48 weight packs ONCE before
// the time loop. R6's in-loop "+v" pins let the allocator reload-from-global
// before every asm; an opaque one-shot def cannot be rematerialized, forcing
// true VGPR residency (R9 showed VGPR_Count=44 -> weights were re-fetched in
// the hot loop = the persistent ~2x VALU inflation).

typedef _Float16 half2v __attribute__((ext_vector_type(2)));

__device__ __forceinline__ float fdot2f(int a, int b, float c) {
    return __builtin_amdgcn_fdot2(__builtin_bit_cast(half2v, a),
                                  __builtin_bit_cast(half2v, b), c, false);
}

__device__ __forceinline__ int pkf16(float lo, float hi) {
    return __builtin_bit_cast(int, __builtin_amdgcn_cvt_pkrtz(lo, hi));
}

// sigmoid(a) = 1/(1+exp(-a)) : mul + exp2 + add + rcp (no IEEE div lowering)
__device__ __forceinline__ float sigm(float a) {
    float e = __builtin_amdgcn_exp2f(a * -1.442695041f);
    return __builtin_amdgcn_rcpf(1.0f + e);
}

#define FOR16(M) M(0) M(1) M(2) M(3) M(4) M(5) M(6) M(7) \
                 M(8) M(9) M(10) M(11) M(12) M(13) M(14) M(15)

__global__ __launch_bounds__(256, 1)
void gru_fused_kernel(const float* __restrict__ x,
                      const float* __restrict__ W_ih,
                      const float* __restrict__ W_hh,
                      const float* __restrict__ b_ih,
                      const float* __restrict__ b_hh,
                      const float* __restrict__ fc_w,
                      const float* __restrict__ fc_b,
                      float* __restrict__ out)
{
    const int tid = threadIdx.x;
    const int j   = tid & 31;                      // hidden index this lane owns
    const int g   = tid >> 5;                      // group (batch slot in block)
    const int bb  = blockIdx.x * 8 + g;            // batch element

    __shared__ float xs[8 * 516];                  // all x for this block (pad 4)
    __shared__ unsigned short hbuf[8][32];         // f16 h per group (64B rows)

    // ---- stage the block's entire x [8 batches x 512 t] into LDS ----
    {
        const float* xbase = x + (size_t)blockIdx.x * 8 * 512;
        #pragma unroll
        for (int k = 0; k < 16; ++k) {
            int idx = tid + k * 256;               // coalesced
            int b   = idx >> 9, p = idx & 511;
            xs[b * 516 + p] = xbase[idx];
        }
    }

    // ---- named packed weight registers (48 ints) ----
#define DECLW(p) int wr##p, wz##p, wn##p;
    FOR16(DECLW)
#undef DECLW

    {
        const float4* wrp = reinterpret_cast<const float4*>(W_hh + (j) * 32);
        const float4* wzp = reinterpret_cast<const float4*>(W_hh + (32 + j) * 32);
        const float4* wnp = reinterpret_cast<const float4*>(W_hh + (64 + j) * 32);
#define INITQ(q, p0, p1)                                \
        {                                               \
            float4 a = wrp[q], b = wzp[q], c = wnp[q];  \
            wr##p0 = pkf16(a.x, a.y);                   \
            wr##p1 = pkf16(a.z, a.w);                   \
            wz##p0 = pkf16(b.x, b.y);                   \
            wz##p1 = pkf16(b.z, b.w);                   \
            wn##p0 = pkf16(c.x, c.y);                   \
            wn##p1 = pkf16(c.z, c.w);                   \
        }
        INITQ(0, 0, 1)  INITQ(1, 2, 3)  INITQ(2, 4, 5)  INITQ(3, 6, 7)
        INITQ(4, 8, 9)  INITQ(5, 10, 11) INITQ(6, 12, 13) INITQ(7, 14, 15)
#undef INITQ
    }

    // ---- OPAQUE one-shot defs: forbid rematerialization of the packs ----
    asm volatile("" : "+v"(wr0),"+v"(wr1),"+v"(wr2),"+v"(wr3),
                      "+v"(wr4),"+v"(wr5),"+v"(wr6),"+v"(wr7),
                      "+v"(wr8),"+v"(wr9),"+v"(wr10),"+v"(wr11),
                      "+v"(wr12),"+v"(wr13),"+v"(wr14),"+v"(wr15));
    asm volatile("" : "+v"(wz0),"+v"(wz1),"+v"(wz2),"+v"(wz3),
                      "+v"(wz4),"+v"(wz5),"+v"(wz6),"+v"(wz7),
                      "+v"(wz8),"+v"(wz9),"+v"(wz10),"+v"(wz11),
                      "+v"(wz12),"+v"(wz13),"+v"(wz14),"+v"(wz15));
    asm volatile("" : "+v"(wn0),"+v"(wn1),"+v"(wn2),"+v"(wn3),
                      "+v"(wn4),"+v"(wn5),"+v"(wn6),"+v"(wn7),
                      "+v"(wn8),"+v"(wn9),"+v"(wn10),"+v"(wn11),
                      "+v"(wn12),"+v"(wn13),"+v"(wn14),"+v"(wn15));

    // biases / input weights (I == 1)
    const float br   = b_ih[j]      + b_hh[j];
    const float bz   = b_ih[32 + j] + b_hh[32 + j];
    const float bin  = b_ih[64 + j];
    const float bhn  = b_hh[64 + j];
    const float wihr = W_ih[j];
    const float wihz = W_ih[32 + j];
    const float wihn = W_ih[64 + j];

    float h = 0.0f;
    hbuf[g][j] = 0;                     // f16 +0.0
    __syncthreads();                    // x staging crosses waves

    for (int c = 0; c < 16; ++c) {
        const float* xc = &xs[g * 516 + c * 32];

        #pragma unroll
        for (int tt = 0; tt < 32; ++tt) {
            float xb = xc[tt];                       // ds_read_b32, imm offset

            // read the whole replicated h row (4 x b128 broadcast reads)
            const int4* hp = reinterpret_cast<const int4*>(&hbuf[g][0]);
            int4 A = hp[0], B = hp[1], C = hp[2], D = hp[3];

            float ar = fmaf(xb, wihr, br);
            float az = fmaf(xb, wihz, bz);
            float an = bhn;
            ar = fdot2f(wr0,  A.x, ar); az = fdot2f(wz0,  A.x, az); an = fdot2f(wn0,  A.x, an);
            ar = fdot2f(wr1,  A.y, ar); az = fdot2f(wz1,  A.y, az); an = fdot2f(wn1,  A.y, an);
            ar = fdot2f(wr2,  A.z, ar); az = fdot2f(wz2,  A.z, az); an = fdot2f(wn2,  A.z, an);
            ar = fdot2f(wr3,  A.w, ar); az = fdot2f(wz3,  A.w, az); an = fdot2f(wn3,  A.w, an);
            ar = fdot2f(wr4,  B.x, ar); az = fdot2f(wz4,  B.x, az); an = fdot2f(wn4,  B.x, an);
            ar = fdot2f(wr5,  B.y, ar); az = fdot2f(wz5,  B.y, az); an = fdot2f(wn5,  B.y, an);
            ar = fdot2f(wr6,  B.z, ar); az = fdot2f(wz6,  B.z, az); an = fdot2f(wn6,  B.z, an);
            ar = fdot2f(wr7,  B.w, ar); az = fdot2f(wz7,  B.w, az); an = fdot2f(wn7,  B.w, an);
            ar = fdot2f(wr8,  C.x, ar); az = fdot2f(wz8,  C.x, az); an = fdot2f(wn8,  C.x, an);
            ar = fdot2f(wr9,  C.y, ar); az = fdot2f(wz9,  C.y, az); an = fdot2f(wn9,  C.y, an);
            ar = fdot2f(wr10, C.z, ar); az = fdot2f(wz10, C.z, az); an = fdot2f(wn10, C.z, an);
            ar = fdot2f(wr11, C.w, ar); az = fdot2f(wz11, C.w, az); an = fdot2f(wn11, C.w, an);
            ar = fdot2f(wr12, D.x, ar); az = fdot2f(wz12, D.x, az); an = fdot2f(wn12, D.x, an);
            ar = fdot2f(wr13, D.y, ar); az = fdot2f(wz13, D.y, az); an = fdot2f(wn13, D.y, an);
            ar = fdot2f(wr14, D.z, ar); az = fdot2f(wz14, D.z, az); an = fdot2f(wn14, D.z, an);
            ar = fdot2f(wr15, D.w, ar); az = fdot2f(wz15, D.w, az); an = fdot2f(wn15, D.w, an);

            float r = sigm(ar);
            float z = sigm(az);
            float npre = fmaf(r, an, fmaf(xb, wihn, bin));
            // tanh(a) = 1 - 2/(1+exp(2a)), exp via exp2, div via rcp
            float e2 = __builtin_amdgcn_exp2f(npre * 2.885390082f);
            float t  = __builtin_amdgcn_rcpf(1.0f + e2);
            float n  = fmaf(-2.0f, t, 1.0f);
            h = fmaf(z, h - n, n);       // h = n + z*(h-n)

            // publish new h as f16 for next step's broadcast reads
            hbuf[g][j] = __builtin_bit_cast(unsigned short, (_Float16)h);
        }
    }

    // ---- FC epilogue: out[bb, c] = sum_j h_j * fc_w[c*32+j] + fc_b[c] ----
    float s0 = h * fc_w[j];
    float s1 = h * fc_w[32 + j];
    #pragma unroll
    for (int off = 16; off >= 1; off >>= 1) {
        s0 += __shfl_xor(s0, off, 32);
        s1 += __shfl_xor(s1, off, 32);
    }
    if (j == 0) {
        out[(size_t)bb * 2 + 0] = s0 + fc_b[0];
        out[(size_t)bb * 2 + 1] = s1 + fc_b[1];
    }
}

extern "C" void kernel_launch(void* const* d_in, const int* in_sizes, int n_in,
                              void* d_out, int out_size, void* d_ws, size_t ws_size,
                              hipStream_t stream)
{
    const float* x    = (const float*)d_in[0];
    const float* W_ih = (const float*)d_in[1];
    const float* W_hh = (const float*)d_in[2];
    const float* b_ih = (const float*)d_in[3];
    const float* b_hh = (const float*)d_in[4];
    const float* fc_w = (const float*)d_in[5];
    const float* fc_b = (const float*)d_in[6];
    float* out = (float*)d_out;

    dim3 grid(512), block(256);
    hipLaunchKernelGGL(gru_fused_kernel, grid, block, 0, stream,
                       x, W_ih, W_hh, b_ih, b_hh, fc_w, fc_b, out);
}